// Round 1
// baseline (1296.897 us; speedup 1.0000x reference)
//
#include <hip/hip_runtime.h>
#include <limits.h>
#include <math.h>

// Problem constants (fixed by the reference setup_inputs)
constexpr int D_ = 4;
constexpr int B_ = 8192;
constexpr int F_ = 128;
constexpr int TILE = 64;     // 64x64 sim tile per block
constexpr int PAD  = 132;    // LDS row stride in floats (132*4=528 B, 16B aligned, bank step 4)

__global__ __launch_bounds__(256, 2)
void mine_hardest(const float* __restrict__ emb,
                  const int*   __restrict__ labels,
                  float*       __restrict__ out)
{
    __shared__ float As[TILE * PAD];
    __shared__ float Bs[TILE * PAD];
    __shared__ int   cl_s[TILE];

    const int tid  = threadIdx.x;
    const int bid  = blockIdx.x;
    const int d    = bid >> 7;        // 128 row-tiles per domain
    const int rt   = bid & 127;
    const int row0 = rt * TILE;

    const float* __restrict__ embD = emb + (size_t)d * B_ * F_;
    const int*   __restrict__ labD = labels + d * B_;

    // ---- stage A (row) tile once: row-major padded, coalesced float4 loads ----
    #pragma unroll
    for (int it = 0; it < 8; ++it) {
        const int flat = it * 256 + tid;   // float4 slot index; 32 float4 per row
        const int r    = flat >> 5;
        const int k4   = flat & 31;
        const float4 v = *(const float4*)(embD + (size_t)(row0 + r) * F_ + (k4 << 2));
        *(float4*)(&As[r * PAD + (k4 << 2)]) = v;
    }

    const int tx  = tid & 15;   // col group (strided micro-tile: cols tx + 16j)
    const int tyg = tid >> 4;   // row group (rows tyg + 16i); within a wave tyg spans 4 values

    int rlab[4], rloc[4];
    #pragma unroll
    for (int i = 0; i < 4; ++i) {
        rloc[i] = row0 + tyg + 16 * i;     // domain-local row index
        rlab[i] = labD[rloc[i]];
    }

    float pmin[4], nmax[4];
    int   pidx[4], nidx[4];
    #pragma unroll
    for (int i = 0; i < 4; ++i) {
        pmin[i] = INFINITY;  pidx[i] = INT_MAX;
        nmax[i] = -INFINITY; nidx[i] = INT_MAX;
    }

    for (int ct = 0; ct < B_ / TILE; ++ct) {
        __syncthreads();   // previous tile's readers done before overwrite
        // ---- stage B (col) tile ----
        #pragma unroll
        for (int it = 0; it < 8; ++it) {
            const int flat = it * 256 + tid;
            const int r    = flat >> 5;
            const int k4   = flat & 31;
            const float4 v = *(const float4*)(embD + (size_t)(ct * TILE + r) * F_ + (k4 << 2));
            *(float4*)(&Bs[r * PAD + (k4 << 2)]) = v;
        }
        if (tid < TILE) cl_s[tid] = labD[ct * TILE + tid];
        __syncthreads();

        float acc[4][4];
        #pragma unroll
        for (int i = 0; i < 4; ++i)
            #pragma unroll
            for (int j = 0; j < 4; ++j) acc[i][j] = 0.f;

        // ---- 64x64 tile dot products, k vectorized by 4 (ds_read_b128) ----
        #pragma unroll 8
        for (int kf = 0; kf < F_; kf += 4) {
            float4 a[4], b[4];
            #pragma unroll
            for (int i = 0; i < 4; ++i)
                a[i] = *(const float4*)(&As[(tyg + 16 * i) * PAD + kf]);
            #pragma unroll
            for (int j = 0; j < 4; ++j)
                b[j] = *(const float4*)(&Bs[(tx + 16 * j) * PAD + kf]);
            #pragma unroll
            for (int i = 0; i < 4; ++i)
                #pragma unroll
                for (int j = 0; j < 4; ++j) {
                    acc[i][j] = fmaf(a[i].x, b[j].x, acc[i][j]);
                    acc[i][j] = fmaf(a[i].y, b[j].y, acc[i][j]);
                    acc[i][j] = fmaf(a[i].z, b[j].z, acc[i][j]);
                    acc[i][j] = fmaf(a[i].w, b[j].w, acc[i][j]);
                }
        }

        // ---- tracker updates (first-occurrence tie-break via index compare) ----
        #pragma unroll
        for (int j = 0; j < 4; ++j) {
            const int jcol = tx + 16 * j;
            const int jl   = ct * TILE + jcol;    // domain-local col index
            const int cl   = cl_s[jcol];
            #pragma unroll
            for (int i = 0; i < 4; ++i) {
                const float s = acc[i][j];
                if (cl == rlab[i]) {
                    if (jl != rloc[i]) {
                        if (s < pmin[i] || (s == pmin[i] && jl < pidx[i])) { pmin[i] = s; pidx[i] = jl; }
                    }
                } else {
                    if (s > nmax[i] || (s == nmax[i] && jl < nidx[i])) { nmax[i] = s; nidx[i] = jl; }
                }
            }
        }
    }

    // ---- reduce across the 16 tx lanes sharing each row (within wave) ----
    #pragma unroll
    for (int off = 1; off < 16; off <<= 1) {
        #pragma unroll
        for (int i = 0; i < 4; ++i) {
            float ov = __shfl_xor(pmin[i], off);
            int   oi = __shfl_xor(pidx[i], off);
            if (ov < pmin[i] || (ov == pmin[i] && oi < pidx[i])) { pmin[i] = ov; pidx[i] = oi; }
            ov = __shfl_xor(nmax[i], off);
            oi = __shfl_xor(nidx[i], off);
            if (ov > nmax[i] || (ov == nmax[i] && oi < nidx[i])) { nmax[i] = ov; nidx[i] = oi; }
        }
    }

    // ---- outputs: [pdist DB][ndist DB][pembed DB*F][nembed DB*F] ----
    float* __restrict__ pd = out;
    float* __restrict__ nd = out + (size_t)D_ * B_;
    float* __restrict__ pe = out + (size_t)2 * D_ * B_;
    float* __restrict__ ne = pe  + (size_t)D_ * B_ * F_;

    #pragma unroll
    for (int i = 0; i < 4; ++i) {
        const bool   has  = (pidx[i] != INT_MAX);     // row has >= 1 positive
        const size_t grow = (size_t)d * B_ + rloc[i]; // global output row
        if (tx == 0) {
            pd[grow] = has ? pmin[i] : 0.f;
            nd[grow] = has ? nmax[i] : 0.f;
        }
        const size_t ob = grow * F_;
        if (has) {
            const int ni = (nidx[i] == INT_MAX) ? 0 : nidx[i];  // degenerate: no negatives
            const float4* sp = (const float4*)(embD + (size_t)pidx[i] * F_);
            const float4* sn = (const float4*)(embD + (size_t)ni      * F_);
            // 16 lanes x 8 floats = 128-float row copy
            *(float4*)(&pe[ob + tx * 8])     = sp[tx * 2];
            *(float4*)(&pe[ob + tx * 8 + 4]) = sp[tx * 2 + 1];
            *(float4*)(&ne[ob + tx * 8])     = sn[tx * 2];
            *(float4*)(&ne[ob + tx * 8 + 4]) = sn[tx * 2 + 1];
        } else {
            const float4 z = make_float4(0.f, 0.f, 0.f, 0.f);
            *(float4*)(&pe[ob + tx * 8])     = z;
            *(float4*)(&pe[ob + tx * 8 + 4]) = z;
            *(float4*)(&ne[ob + tx * 8])     = z;
            *(float4*)(&ne[ob + tx * 8 + 4]) = z;
        }
    }
}

extern "C" void kernel_launch(void* const* d_in, const int* in_sizes, int n_in,
                              void* d_out, int out_size, void* d_ws, size_t ws_size,
                              hipStream_t stream) {
    const float* emb    = (const float*)d_in[0];
    const int*   labels = (const int*)d_in[1];
    float*       out    = (float*)d_out;

    const dim3 grid(D_ * (B_ / TILE));   // 4 * 128 = 512 blocks
    mine_hardest<<<grid, 256, 0, stream>>>(emb, labels, out);
}

// Round 3
// 614.692 us; speedup vs baseline: 2.1098x; 2.1098x over previous
//
#include <hip/hip_runtime.h>
#include <limits.h>
#include <math.h>
#include <stdint.h>

// Problem constants (fixed by reference setup_inputs)
constexpr int D_ = 4;
constexpr int B_ = 8192;
constexpr int F_ = 128;
constexpr int BM = 64;             // rows per block
constexpr int BN = 64;             // cols per tile step
constexpr int NCT = B_ / BN;       // 128 col tiles
constexpr float LO_SCALE = 4096.f; // 2^12 keeps lo out of f16 subnormals
constexpr float LO_INV = 1.f / 4096.f;

typedef _Float16 f16x8 __attribute__((ext_vector_type(8)));
typedef float f32x16 __attribute__((ext_vector_type(16)));

// C/D layout for mfma_f32_32x32x16 (m74/m101 verified):
//   col = lane&31, row = (reg&3) + 8*(reg>>2) + 4*(lane>>5)
__device__ __host__ constexpr int ROFS(int reg) { return (reg & 3) + 8 * (reg >> 2); }

// ---- pass 1: fp32 -> (hi, lo*4096) f16 split ----
__global__ __launch_bounds__(256)
void convert_f16(const float* __restrict__ src,
                 _Float16* __restrict__ hi, _Float16* __restrict__ lo) {
    const size_t i0 = ((size_t)blockIdx.x * 256 + threadIdx.x) * 8;
    const float4 a = *(const float4*)(src + i0);
    const float4 b = *(const float4*)(src + i0 + 4);
    const float xs[8] = {a.x, a.y, a.z, a.w, b.x, b.y, b.z, b.w};
    f16x8 h, l;
    #pragma unroll
    for (int k = 0; k < 8; ++k) {
        const _Float16 hh = (_Float16)xs[k];
        h[k] = hh;
        l[k] = (_Float16)((xs[k] - (float)hh) * LO_SCALE);
    }
    *(f16x8*)(hi + i0) = h;
    *(f16x8*)(lo + i0) = l;
}

// ---- pass 2: mine hardest pos/neg via 32x32x16 MFMA ----
template <bool PRE>
__global__ __launch_bounds__(256, 2)
void mine_mfma(const float* __restrict__ emb,
               const _Float16* __restrict__ Ehi,
               const _Float16* __restrict__ Elo,
               const int* __restrict__ labels,
               float* __restrict__ out) {
    // swizzled B tile: slot(r, g) = r*16 + (g ^ (r&15)); 16 B per slot
    __shared__ f16x8 BhiS[1024];          // 16 KB
    __shared__ f16x8 BloS[1024];          // 16 KB
    __shared__ float mrgF[2][2][16][4];   // [wr][h][reg][pmin,pidx,nmax,nidx]
    __shared__ int   rowinfo[64][2];      // [rowInBlock][pidx_or_-1, nidx]

    const int tid = threadIdx.x;
    const int lane = tid & 63;
    const int wid = tid >> 6;
    const int wr = wid >> 1, wc = wid & 1;  // 2x2 wave grid, 32x32 out each
    const int l31 = lane & 31, h = lane >> 5;

    const int bid = blockIdx.x;
    const int d = bid >> 7;
    const int rt = bid & 127;
    const int row0 = rt * BM;

    const float* __restrict__ embD = emb + (size_t)d * B_ * F_;
    const _Float16* __restrict__ EhiD = Ehi + (size_t)d * B_ * F_;
    const _Float16* __restrict__ EloD = Elo + (size_t)d * B_ * F_;
    const int* __restrict__ labD = labels + d * B_;

    // ---- A fragments in registers: lane holds A[row=l31][k = ks*16 + h*8 + e] ----
    const int arow = row0 + wr * 32 + l31;
    f16x8 Ah[8], Al[8];
    #pragma unroll
    for (int ks = 0; ks < 8; ++ks) {
        if constexpr (PRE) {
            Ah[ks] = *(const f16x8*)(EhiD + (size_t)arow * F_ + ks * 16 + h * 8);
            Al[ks] = *(const f16x8*)(EloD + (size_t)arow * F_ + ks * 16 + h * 8);
        } else {
            const float* p = embD + (size_t)arow * F_ + ks * 16 + h * 8;
            const float4 x = *(const float4*)p;
            const float4 y = *(const float4*)(p + 4);
            const float xs[8] = {x.x, x.y, x.z, x.w, y.x, y.y, y.z, y.w};
            #pragma unroll
            for (int k = 0; k < 8; ++k) {
                const _Float16 hh = (_Float16)xs[k];
                Ah[ks][k] = hh;
                Al[ks][k] = (_Float16)((xs[k] - (float)hh) * LO_SCALE);
            }
        }
    }

    // ---- per-lane output rows (C layout) & their labels ----
    const int rbase = row0 + wr * 32 + 4 * h;
    int rlab[16];
    #pragma unroll
    for (int reg = 0; reg < 16; ++reg) rlab[reg] = labD[rbase + ROFS(reg)];

    float pmin[16], nmax[16];
    int pidx[16], nidx[16];
    #pragma unroll
    for (int reg = 0; reg < 16; ++reg) {
        pmin[reg] = INFINITY;  pidx[reg] = INT_MAX;
        nmax[reg] = -INFINITY; nidx[reg] = INT_MAX;
    }

    // ---- staging slots: global-linear source, swizzled LDS dest ----
    int sr[4], sg[4], sslot[4];
    #pragma unroll
    for (int i = 0; i < 4; ++i) {
        const int flat = i * 256 + tid;
        sr[i] = flat >> 4;
        sg[i] = flat & 15;
        sslot[i] = sr[i] * 16 + (sg[i] ^ (sr[i] & 15));
    }

    f16x8 sh[4], sl[4];
    auto loadStage = [&](int ct) {
        #pragma unroll
        for (int i = 0; i < 4; ++i) {
            if constexpr (PRE) {
                sh[i] = *(const f16x8*)(EhiD + (size_t)(ct * 64 + sr[i]) * F_ + sg[i] * 8);
                sl[i] = *(const f16x8*)(EloD + (size_t)(ct * 64 + sr[i]) * F_ + sg[i] * 8);
            } else {
                const float* p = embD + (size_t)(ct * 64 + sr[i]) * F_ + sg[i] * 8;
                const float4 x = *(const float4*)p;
                const float4 y = *(const float4*)(p + 4);
                const float xs[8] = {x.x, x.y, x.z, x.w, y.x, y.y, y.z, y.w};
                #pragma unroll
                for (int k = 0; k < 8; ++k) {
                    const _Float16 hh = (_Float16)xs[k];
                    sh[i][k] = hh;
                    sl[i][k] = (_Float16)((xs[k] - (float)hh) * LO_SCALE);
                }
            }
        }
    };
    auto writeStage = [&]() {
        #pragma unroll
        for (int i = 0; i < 4; ++i) {
            BhiS[sslot[i]] = sh[i];
            BloS[sslot[i]] = sl[i];
        }
    };

    const int brow = wc * 32 + l31;          // tile-local col (= B row)
    const int bswz = brow & 15;

    // ---- main loop: reg-staged double buffer, plain __syncthreads ----
    loadStage(0);
    for (int ct = 0; ct < NCT; ++ct) {
        __syncthreads();            // previous tile's LDS readers done
        writeStage();
        __syncthreads();            // tile visible to all waves
        if (ct + 1 < NCT) loadStage(ct + 1);   // issue-early (hides HBM/L2 latency)

        f32x16 a1, a2;
        #pragma unroll
        for (int r = 0; r < 16; ++r) { a1[r] = 0.f; a2[r] = 0.f; }

        #pragma unroll
        for (int ks = 0; ks < 8; ++ks) {
            const int g = 2 * ks + h;
            const f16x8 bh = BhiS[brow * 16 + (g ^ bswz)];
            const f16x8 bl = BloS[brow * 16 + (g ^ bswz)];
            a1 = __builtin_amdgcn_mfma_f32_32x32x16_f16(Ah[ks], bh, a1, 0, 0, 0);
            a2 = __builtin_amdgcn_mfma_f32_32x32x16_f16(Ah[ks], bl, a2, 0, 0, 0);
            a2 = __builtin_amdgcn_mfma_f32_32x32x16_f16(Al[ks], bh, a2, 0, 0, 0);
        }

        const int jl = ct * 64 + brow;       // domain-local col index
        const int cl = labD[jl];             // col label (L1/L2-hot)

        if (ct == rt) {
            #pragma unroll
            for (int reg = 0; reg < 16; ++reg) {
                const float s = fmaf(a2[reg], LO_INV, a1[reg]);
                const bool same = (cl == rlab[reg]);
                const bool self = (jl == rbase + ROFS(reg));
                const float ps = (same && !self) ? s : INFINITY;
                if (ps < pmin[reg]) { pmin[reg] = ps; pidx[reg] = jl; }
                const float ns = same ? -INFINITY : s;
                if (ns > nmax[reg]) { nmax[reg] = ns; nidx[reg] = jl; }
            }
        } else {
            #pragma unroll
            for (int reg = 0; reg < 16; ++reg) {
                const float s = fmaf(a2[reg], LO_INV, a1[reg]);
                const bool same = (cl == rlab[reg]);
                const float ps = same ? INFINITY : s;        // inverted roles below
                const float ns = same ? -INFINITY : s;
                const float pp = same ? s : INFINITY;
                if (pp < pmin[reg]) { pmin[reg] = pp; pidx[reg] = jl; }
                if (ns > nmax[reg]) { nmax[reg] = ns; nidx[reg] = jl; }
                (void)ps;
            }
        }
    }

    // ---- in-wave reduce across the 32 col-lanes of each half ----
    #pragma unroll
    for (int off = 1; off < 32; off <<= 1)
        #pragma unroll
        for (int reg = 0; reg < 16; ++reg) {
            float ov = __shfl_xor(pmin[reg], off);
            int oi = __shfl_xor(pidx[reg], off);
            if (ov < pmin[reg]) { pmin[reg] = ov; pidx[reg] = oi; }
            ov = __shfl_xor(nmax[reg], off);
            oi = __shfl_xor(nidx[reg], off);
            if (ov > nmax[reg]) { nmax[reg] = ov; nidx[reg] = oi; }
        }

    // ---- cross-wave merge (wc=1 -> LDS -> wc=0): THE R2 bug fix ----
    __syncthreads();
    if (wc == 1) {
        #pragma unroll
        for (int reg = 0; reg < 16; ++reg)
            if (l31 == reg) {
                mrgF[wr][h][reg][0] = pmin[reg];
                mrgF[wr][h][reg][1] = __int_as_float(pidx[reg]);
                mrgF[wr][h][reg][2] = nmax[reg];
                mrgF[wr][h][reg][3] = __int_as_float(nidx[reg]);
            }
    }
    __syncthreads();

    float* __restrict__ pd = out;
    float* __restrict__ nd = out + (size_t)D_ * B_;
    float* __restrict__ pe = out + (size_t)2 * D_ * B_;
    float* __restrict__ ne = pe + (size_t)D_ * B_ * F_;

    if (wc == 0) {
        #pragma unroll
        for (int reg = 0; reg < 16; ++reg) {
            const float ov = mrgF[wr][h][reg][0];
            const int oi = __float_as_int(mrgF[wr][h][reg][1]);
            if (ov < pmin[reg]) { pmin[reg] = ov; pidx[reg] = oi; }
            const float on = mrgF[wr][h][reg][2];
            const int oni = __float_as_int(mrgF[wr][h][reg][3]);
            if (on > nmax[reg]) { nmax[reg] = on; nidx[reg] = oni; }
        }
        #pragma unroll
        for (int reg = 0; reg < 16; ++reg)
            if (l31 == reg) {
                const int rib = wr * 32 + 4 * h + ROFS(reg);
                const bool has = (pidx[reg] != INT_MAX);
                const size_t grow = (size_t)d * B_ + row0 + rib;
                pd[grow] = has ? pmin[reg] : 0.f;
                nd[grow] = has ? nmax[reg] : 0.f;
                rowinfo[rib][0] = has ? pidx[reg] : -1;
                rowinfo[rib][1] = (nidx[reg] == INT_MAX) ? 0 : nidx[reg];
            }
    }
    __syncthreads();

    // ---- cooperative embedding gathers: 256 threads, 64 rows x 2 arrays ----
    {
        const int r = tid >> 2;          // row in block
        const int part = tid & 3;        // 32-float quarter
        const int pi = rowinfo[r][0];
        const int ni = rowinfo[r][1];
        const size_t ob = ((size_t)d * B_ + row0 + r) * F_ + part * 32;
        const float4 zv = make_float4(0.f, 0.f, 0.f, 0.f);
        const float4* sp = (const float4*)(embD + (size_t)(pi < 0 ? 0 : pi) * F_ + part * 32);
        const float4* sn = (const float4*)(embD + (size_t)ni * F_ + part * 32);
        #pragma unroll
        for (int q = 0; q < 8; ++q) {
            *(float4*)(&pe[ob + q * 4]) = (pi >= 0) ? sp[q] : zv;
            *(float4*)(&ne[ob + q * 4]) = (pi >= 0) ? sn[q] : zv;
        }
    }
}

extern "C" void kernel_launch(void* const* d_in, const int* in_sizes, int n_in,
                              void* d_out, int out_size, void* d_ws, size_t ws_size,
                              hipStream_t stream) {
    const float* emb = (const float*)d_in[0];
    const int* labels = (const int*)d_in[1];
    float* out = (float*)d_out;

    const size_t NE = (size_t)D_ * B_ * F_;
    const bool ws_ok = ws_size >= NE * 2 * sizeof(_Float16);  // 16.8 MB

    if (ws_ok) {
        _Float16* Ehi = (_Float16*)d_ws;
        _Float16* Elo = Ehi + NE;
        convert_f16<<<dim3((unsigned)(NE / 2048)), 256, 0, stream>>>(emb, Ehi, Elo);
        mine_mfma<true><<<dim3(D_ * (B_ / BM)), 256, 0, stream>>>(emb, Ehi, Elo, labels, out);
    } else {
        mine_mfma<false><<<dim3(D_ * (B_ / BM)), 256, 0, stream>>>(emb, nullptr, nullptr, labels, out);
    }
}